// Round 2
// baseline (155.562 us; speedup 1.0000x reference)
//
#include <hip/hip_runtime.h>

#define WG 256
#define G64 64     // num_graphs (fixed by problem)
#define SPLITS 16  // blocks per graph in k_acc

// ---------------------------------------------------------------------------
// k_bucket: one thread per edge. g = batch[src]; block-aggregated cursor bump
// (64 global atomics per block); stores the int2 endpoint indices at the
// claimed slot (x is 600 KB -> L2-resident, k_acc gathers coords itself).
// Blocks 0..63 additionally zero out[g]'s 4 KB slab (replaces the memset
// dispatch; k_acc runs after us in stream order so visibility is guaranteed).
// Block 0 computes node_off[g] = lower_bound(batch, g).
// ---------------------------------------------------------------------------
__global__ __launch_bounds__(WG) void k_bucket(const int* __restrict__ edge,
                                               const int* __restrict__ batch,
                                               int2* __restrict__ bucket,
                                               int* __restrict__ cursor,
                                               int* __restrict__ node_off,
                                               float* __restrict__ out,
                                               int E, int N, int CAP) {
    __shared__ int lc[G64], lb[G64];
    int tid = threadIdx.x;
    int bid = blockIdx.x;
    if (tid < G64) lc[tid] = 0;

    if (bid < G64) {  // zero this graph's output slab (1024 floats)
        float4* o4 = (float4*)(out + ((size_t)bid << 10));
        o4[tid] = make_float4(0.f, 0.f, 0.f, 0.f);
    }
    __syncthreads();

    int e = bid * WG + tid;
    int g = 0, r = 0, s = 0, d = 0;
    if (e < E) {
        s = edge[e];
        d = edge[E + e];
        g = batch[s];
        r = atomicAdd(&lc[g], 1);
    }
    __syncthreads();
    if (tid < G64 && lc[tid]) lb[tid] = atomicAdd(&cursor[tid], lc[tid]);
    __syncthreads();
    if (e < E) {
        int pos = lb[g] + r;
        if (pos < CAP) bucket[(size_t)g * CAP + pos] = make_int2(s, d);
    }

    if (bid == 0 && tid <= G64) {
        int lo = 0, hi = N;
        while (lo < hi) {
            int mid = (lo + hi) >> 1;
            if (batch[mid] < tid) lo = mid + 1; else hi = mid;
        }
        node_off[tid] = lo;
    }
}

// ---------------------------------------------------------------------------
// k_acc: block (g, split). The clamped-linear sigmoid profile over the 32
// thresholds is a step function with exactly 3 non-zero DELTAS per item:
//   d[bF]   = s0          (true sigmoid at bF,   1/(1+e0))
//   d[bF+1] = s1 - s0     (true sigmoid at bF+1, 1/(1+e0*fstep))
//   d[bF+2] = 1 - s1
// where bF = floor((h - lin0)/dlin). val(b) = prefix_{i<=b} d[i]; clamping
// indices into [0, 33] (slot 33 = dump row) reproduces exact-0/exact-1
// saturation on both ends (error <= one exp-step = 6.8e-7 per item).
// So per item-lane: 1 exp2 + 2 rcp + 3 LDS float atomics (banks = t ->
// conflict-free per half-wave) instead of 32x(fma+med3+add).
// Epilogue: in-place prefix over b per t-lane, then 1024 global atomics.
// Nodes add (+), edges add (-) into the same histogram.
// ---------------------------------------------------------------------------
__global__ __launch_bounds__(WG) void k_acc(const float* __restrict__ x,
                                            const float* __restrict__ v,
                                            const int2* __restrict__ bucket,
                                            const float* __restrict__ lin,
                                            const int* __restrict__ cursor,
                                            const int* __restrict__ node_off,
                                            float* __restrict__ out, int CAP) {
    __shared__ float hist[34 * 32];   // [delta-slot 0..33][t]
    int tid = threadIdx.x;
    for (int i = tid; i < 34 * 32; i += WG) hist[i] = 0.f;

    int g = blockIdx.x;
    int n0 = node_off[g], n1 = node_off[g + 1];
    int nn = n1 - n0;
    int ne = cursor[g]; if (ne > CAP) ne = CAP;
    int L = nn + ne;
    int ipc = (L + SPLITS - 1) / SPLITS;
    int lo = blockIdx.y * ipc;
    int hi = lo + ipc; if (hi > L) hi = L;

    int t = tid & 31, sub = tid >> 5;
    float v0 = v[t], v1 = v[32 + t], v2 = v[64 + t];

    float lin0 = lin[0];
    float dlin = lin[1] - lin[0];                 // > 0
    const float LOG2E = 1.4426950408889634f;
    float d2 = 200.f * dlin * LOG2E;              // exp-step in log2 units (~20.5)
    float inv_dlin = 1.f / dlin;
    float fstep = exp2f(-d2);                     // e-ratio per threshold (6.8e-7)
    __syncthreads();

    // ---- node items (+) ----
    int nhi = hi < nn ? hi : nn;
    for (int idx = lo + sub; idx < nhi; idx += 8) {
        const float* xr = x + (size_t)(n0 + idx) * 3;
        float h = xr[0] * v0 + xr[1] * v1 + xr[2] * v2;
        float bs = (h - lin0) * inv_dlin;
        float bF = floorf(bs);
        float e0 = exp2f((bs - bF) * d2);
        float s0 = __builtin_amdgcn_rcpf(1.f + e0);
        float s1 = __builtin_amdgcn_rcpf(fmaf(e0, fstep, 1.f));
        int ib = (int)bF;
        int i0 = min(33, max(0, ib));
        int i1 = min(33, max(0, ib + 1));
        int i2 = min(33, max(0, ib + 2));
        atomicAdd(&hist[i0 * 32 + t], s0);
        atomicAdd(&hist[i1 * 32 + t], s1 - s0);
        atomicAdd(&hist[i2 * 32 + t], 1.f - s1);
    }

    // ---- edge items (-) ----
    int elo = lo > nn ? lo : nn;
    for (int idx = elo + sub; idx < hi; idx += 8) {
        int2 sd = bucket[(size_t)g * CAP + (idx - nn)];
        const float* xs = x + (size_t)sd.x * 3;
        const float* xd = x + (size_t)sd.y * 3;
        float hs = xs[0] * v0 + xs[1] * v1 + xs[2] * v2;
        float hd = xd[0] * v0 + xd[1] * v1 + xd[2] * v2;
        float h = fmaxf(hs, hd);
        float bs = (h - lin0) * inv_dlin;
        float bF = floorf(bs);
        float e0 = exp2f((bs - bF) * d2);
        float s0 = __builtin_amdgcn_rcpf(1.f + e0);
        float s1 = __builtin_amdgcn_rcpf(fmaf(e0, fstep, 1.f));
        int ib = (int)bF;
        int i0 = min(33, max(0, ib));
        int i1 = min(33, max(0, ib + 1));
        int i2 = min(33, max(0, ib + 2));
        atomicAdd(&hist[i0 * 32 + t], -s0);
        atomicAdd(&hist[i1 * 32 + t], s0 - s1);
        atomicAdd(&hist[i2 * 32 + t], s1 - 1.f);
    }

    __syncthreads();
    // in-place prefix over b (per t): P[b][t] = sum_{i<=b} hist[i][t]
    if (tid < 32) {
        float run = 0.f;
#pragma unroll
        for (int b = 0; b < 32; ++b) {
            run += hist[b * 32 + tid];
            hist[b * 32 + tid] = run;
        }
    }
    __syncthreads();
    for (int c = tid; c < 1024; c += WG)
        unsafeAtomicAdd(&out[((size_t)g << 10) + c], hist[c]);
}

extern "C" void kernel_launch(void* const* d_in, const int* in_sizes, int n_in,
                              void* d_out, int out_size, void* d_ws, size_t ws_size,
                              hipStream_t stream) {
    const int*   edge  = (const int*)d_in[3];
    const int*   batch = (const int*)d_in[4];
    const float* x     = (const float*)d_in[0];
    const float* v     = (const float*)d_in[1];
    const float* lin   = (const float*)d_in[2];
    int N = in_sizes[4];
    int E = in_sizes[3] / 2;

    float* out = (float*)d_out;

    // workspace: [cursor 64][node_off 65][pad to 1024B][bucket G64*CAP*8B]
    int* cursor   = (int*)d_ws;
    int* node_off = cursor + G64;
    int2* bucket  = (int2*)((char*)d_ws + 1024);
    long long cap_ws = (long long)((ws_size - 1024) / ((size_t)G64 * sizeof(int2)));
    int CAP = (int)(cap_ws < (long long)E ? cap_ws : (long long)E);

    hipMemsetAsync(cursor, 0, G64 * sizeof(int), stream);

    k_bucket<<<(E + WG - 1) / WG, WG, 0, stream>>>(edge, batch, bucket, cursor,
                                                   node_off, out, E, N, CAP);
    dim3 grid(G64, SPLITS);
    k_acc<<<grid, WG, 0, stream>>>(x, v, bucket, lin, cursor, node_off, out, CAP);
}

// Round 3
// 94.955 us; speedup vs baseline: 1.6383x; 1.6383x over previous
//
#include <hip/hip_runtime.h>

#define WG 256
#define G64 64     // num_graphs (fixed by problem)
#define SPLITS 16  // blocks per graph in k_acc

// ---------------------------------------------------------------------------
// k_bucket: one thread per edge. g = batch[src]; block-aggregated cursor bump
// (64 global atomics per block); stores the int2 endpoint indices at the
// claimed slot (x is 600 KB -> L2-resident, k_acc gathers coords itself).
// Blocks 0..63 additionally zero out[g]'s 4 KB slab (replaces the memset
// dispatch; k_acc runs after us in stream order so visibility is guaranteed).
// Block 0 computes node_off[g] = lower_bound(batch, g).
// ---------------------------------------------------------------------------
__global__ __launch_bounds__(WG) void k_bucket(const int* __restrict__ edge,
                                               const int* __restrict__ batch,
                                               int2* __restrict__ bucket,
                                               int* __restrict__ cursor,
                                               int* __restrict__ node_off,
                                               float* __restrict__ out,
                                               int E, int N, int CAP) {
    __shared__ int lc[G64], lb[G64];
    int tid = threadIdx.x;
    int bid = blockIdx.x;
    if (tid < G64) lc[tid] = 0;

    if (bid < G64) {  // zero this graph's output slab (1024 floats)
        float4* o4 = (float4*)(out + ((size_t)bid << 10));
        o4[tid] = make_float4(0.f, 0.f, 0.f, 0.f);
    }
    __syncthreads();

    int e = bid * WG + tid;
    int g = 0, r = 0, s = 0, d = 0;
    if (e < E) {
        s = edge[e];
        d = edge[E + e];
        g = batch[s];
        r = atomicAdd(&lc[g], 1);
    }
    __syncthreads();
    if (tid < G64 && lc[tid]) lb[tid] = atomicAdd(&cursor[tid], lc[tid]);
    __syncthreads();
    if (e < E) {
        int pos = lb[g] + r;
        if (pos < CAP) bucket[(size_t)g * CAP + pos] = make_int2(s, d);
    }

    if (bid == 0 && tid <= G64) {
        int lo = 0, hi = N;
        while (lo < hi) {
            int mid = (lo + hi) >> 1;
            if (batch[mid] < tid) lo = mid + 1; else hi = mid;
        }
        node_off[tid] = lo;
    }
}

// ---------------------------------------------------------------------------
// k_acc: block (g, split) -> pure REGISTER accumulation acc[32] (the proven
// round-1 path; LDS float atomics lower to CAS loops without unsafe-fp-atomics
// and serialized 7x worse — do not reintroduce them).
// Sigmoid trick: threshold spacing D = 200*dlin = 14.19 exp-units, so at most
// TWO thresholds (bF = floor(b*), bF+1) are non-saturated. Compute the true
// sigmoids s0,s1 there (1 exp2 + 2 rcp) and use
//   val(b) = clamp(s0 + (b-bF)*(s1-s0), 0, 1)
// exact at bF,bF+1; off by <= 6.8e-7 elsewhere. Per threshold: fma+med3+add,
// all full-rate VALU, statically indexed (acc stays in registers).
// ---------------------------------------------------------------------------
__global__ __launch_bounds__(WG) void k_acc(const float* __restrict__ x,
                                            const float* __restrict__ v,
                                            const int2* __restrict__ bucket,
                                            const float* __restrict__ lin,
                                            const int* __restrict__ cursor,
                                            const int* __restrict__ node_off,
                                            float* __restrict__ out, int CAP) {
    int g = blockIdx.x;
    int n0 = node_off[g], n1 = node_off[g + 1];
    int nn = n1 - n0;
    int ne = cursor[g]; if (ne > CAP) ne = CAP;
    int L = nn + ne;
    int ipc = (L + SPLITS - 1) / SPLITS;
    int lo = blockIdx.y * ipc;
    int hi = lo + ipc; if (hi > L) hi = L;

    int tid = threadIdx.x, t = tid & 31, sub = tid >> 5;
    float v0 = v[t], v1 = v[32 + t], v2 = v[64 + t];

    float lin0 = lin[0];
    float dlin = lin[1] - lin[0];                 // > 0
    const float LOG2E = 1.4426950408889634f;
    float d2 = 200.f * dlin * LOG2E;              // exp-step in log2 units (~20.5)
    float inv_dlin = 1.f / dlin;
    float fstep = exp2f(-d2);                     // e-ratio per threshold (6.8e-7)

    float acc[32];
#pragma unroll
    for (int b = 0; b < 32; ++b) acc[b] = 0.f;

    // ---- node items (+): heights from contiguous x rows ----
    int nhi = hi < nn ? hi : nn;
    for (int idx = lo + sub; idx < nhi; idx += 8) {
        const float* xr = x + (size_t)(n0 + idx) * 3;
        float h = xr[0] * v0 + xr[1] * v1 + xr[2] * v2;
        float bs = (h - lin0) * inv_dlin;         // b* where sigmoid = 0.5
        float bF = floorf(bs);
        float e0 = exp2f((bs - bF) * d2);         // in [1, 2^20.5)
        float s0 = __builtin_amdgcn_rcpf(1.f + e0);             // sigmoid at bF
        float s1 = __builtin_amdgcn_rcpf(fmaf(e0, fstep, 1.f)); // sigmoid at bF+1
        float m = s1 - s0;
        float base = fmaf(-bF, m, s0);
#pragma unroll
        for (int b = 0; b < 32; ++b)
            acc[b] += __builtin_amdgcn_fmed3f(fmaf(m, (float)b, base), 0.f, 1.f);
    }

    // ---- edge items (-): height = max over two endpoints (L2 gathers) ----
    int elo = lo > nn ? lo : nn;
    for (int idx = elo + sub; idx < hi; idx += 8) {
        int2 sd = bucket[(size_t)g * CAP + (idx - nn)];
        const float* xs = x + (size_t)sd.x * 3;
        const float* xd = x + (size_t)sd.y * 3;
        float hs = xs[0] * v0 + xs[1] * v1 + xs[2] * v2;
        float hd = xd[0] * v0 + xd[1] * v1 + xd[2] * v2;
        float h = fmaxf(hs, hd);
        float bs = (h - lin0) * inv_dlin;
        float bF = floorf(bs);
        float e0 = exp2f((bs - bF) * d2);
        float s0 = __builtin_amdgcn_rcpf(1.f + e0);
        float s1 = __builtin_amdgcn_rcpf(fmaf(e0, fstep, 1.f));
        float m = -(s1 - s0);                     // sign folded into slope
        float base = fmaf(-bF, m, -s0);           // -(s0 - bF*(s1-s0))
#pragma unroll
        for (int b = 0; b < 32; ++b)
            acc[b] += __builtin_amdgcn_fmed3f(fmaf(m, (float)b, base), -1.f, 0.f);
    }

    // --- block reduce + flush: shfl halves -> LDS stage[4][32b][32t] -> atomics
    __shared__ float stage[4 * 1024];
#pragma unroll
    for (int b = 0; b < 32; ++b) acc[b] += __shfl_xor(acc[b], 32, 64);
    int w = tid >> 6;
    if ((tid & 32) == 0) {
#pragma unroll
        for (int b = 0; b < 32; ++b) stage[(w << 10) + (b << 5) + t] = acc[b];
    }
    __syncthreads();
    for (int c = tid; c < 1024; c += WG) {
        float s = stage[c] + stage[1024 + c] + stage[2048 + c] + stage[3072 + c];
        unsafeAtomicAdd(&out[((size_t)g << 10) + c], s);
    }
}

extern "C" void kernel_launch(void* const* d_in, const int* in_sizes, int n_in,
                              void* d_out, int out_size, void* d_ws, size_t ws_size,
                              hipStream_t stream) {
    const float* x     = (const float*)d_in[0];
    const float* v     = (const float*)d_in[1];
    const float* lin   = (const float*)d_in[2];
    const int*   edge  = (const int*)d_in[3];
    const int*   batch = (const int*)d_in[4];
    int N = in_sizes[4];
    int E = in_sizes[3] / 2;

    float* out = (float*)d_out;

    // workspace: [cursor 64][node_off 65][pad to 1024B][bucket G64*CAP*8B]
    int* cursor   = (int*)d_ws;
    int* node_off = cursor + G64;
    int2* bucket  = (int2*)((char*)d_ws + 1024);
    long long cap_ws = (long long)((ws_size - 1024) / ((size_t)G64 * sizeof(int2)));
    int CAP = (int)(cap_ws < (long long)E ? cap_ws : (long long)E);

    hipMemsetAsync(cursor, 0, G64 * sizeof(int), stream);

    k_bucket<<<(E + WG - 1) / WG, WG, 0, stream>>>(edge, batch, bucket, cursor,
                                                   node_off, out, E, N, CAP);
    dim3 grid(G64, SPLITS);
    k_acc<<<grid, WG, 0, stream>>>(x, v, bucket, lin, cursor, node_off, out, CAP);
}